// Round 5
// baseline (558.269 us; speedup 1.0000x reference)
//
#include <hip/hip_runtime.h>
#include <stdint.h>

// Binarized dense: C[r][u] = sum_k sign(x[r][k]) * sign(W[k][u]) + b[u]
//   sign(v) = +1 if v >= 0 else -1   -> bit(v) = (v < 0)
//   dot = F - 2 * popcount(xbits ^ wbits)
//
// Packed layout per row/col (F=4096 bits = 64 u64 words):
//   u64 word w = c'*4 + j, c' = 256-float chunk, j = float4 component;
//   bit i of word = bit(v[c'*256 + i*4 + j])  (i = lane of the ballot).
// pack_w reproduces this mapping bit-exactly (verified rounds 1/3/4).
//
// Fused kernel: block = 64 rows x 512 cols, K chunked 8 x 512 floats.
// Per chunk: issue next-chunk global loads (regs) -> compute current from
// LDS dbuf -> finish (ballot/ds_write) -> barrier.  x read from HBM once.

#define BATCH  16384
#define INF    4096
#define UNITS  512
#define KW     128      // u32 words per row (4096/32)
#define KW64   64       // u64 words per row
#define ROWS   64       // x rows per block
#define KC     16       // u32 words per K-chunk (512 floats)
#define NCH    8        // chunks (8*16 = 128 words)
#define PAD    20       // LDS row stride in u32: 5 x 16B slots, odd -> conflict-free

// ---------------- pack W: [4096,512] f32 -> [512,64] u64 --------------------
__global__ __launch_bounds__(256) void pack_w_kernel(const float* __restrict__ W,
                                                     unsigned long long* __restrict__ Wp) {
    int t  = blockIdx.x * 256 + threadIdx.x;   // 0..32767
    int u  = t & 511;                          // column
    int cj = t >> 9;                           // 0..63 = c*4 + j
    int j  = cj & 3;
    int c  = cj >> 2;
    const float* base = W + (size_t)(c * 256 + j) * UNITS + u;
    unsigned long long m = 0;
    #pragma unroll 16
    for (int i = 0; i < 64; ++i) {
        float v = base[(size_t)(4 * i) * UNITS];
        m |= (unsigned long long)(v < 0.f) << i;
    }
    Wp[(size_t)u * KW64 + cj] = m;
}

// ------------------------------ fused kernel --------------------------------
__global__ __launch_bounds__(512, 2) void fused_kernel(const float* __restrict__ x,
                                                       const uint32_t* __restrict__ Wp,
                                                       const float* __restrict__ bias,
                                                       float* __restrict__ C) {
    __shared__ uint32_t sX[2][ROWS][PAD];    // 10 KB
    __shared__ uint32_t sW[2][UNITS][PAD];   // 80 KB
    const int t  = threadIdx.x;
    const int w  = t >> 6;      // wave 0..7 (packs rows w*8..w*8+7)
    const int l  = t & 63;
    const int tx = t & 31;      // output cols tx + 32j, j = 0..15
    const int ty = t >> 5;      // output rows ty + 16i, i = 0..3
    const int row0 = blockIdx.x * ROWS;

    int acc[4][16] = {};

    // ---- prologue: pack chunk 0, stage W chunk 0 (synchronous) ----
    #pragma unroll
    for (int rr = 0; rr < 8; ++rr) {
        const float4* src = reinterpret_cast<const float4*>(
            x + (size_t)(row0 + w * 8 + rr) * INF);
        #pragma unroll
        for (int h = 0; h < 2; ++h) {
            float4 v = src[h * 64 + l];
            unsigned long long b0 = __ballot(v.x < 0.f);
            unsigned long long b1 = __ballot(v.y < 0.f);
            unsigned long long b2 = __ballot(v.z < 0.f);
            unsigned long long b3 = __ballot(v.w < 0.f);
            if (l == 0) {
                uint64_t* d = reinterpret_cast<uint64_t*>(&sX[0][w * 8 + rr][h * 8]);
                d[0] = b0; d[1] = b1; d[2] = b2; d[3] = b3;
            }
        }
    }
    #pragma unroll
    for (int i = 0; i < 4; ++i) {
        int idx = t + 512 * i;             // 0..2047 uint4
        int row = idx >> 2, c4 = idx & 3;
        uint4 v = reinterpret_cast<const uint4*>(Wp + (size_t)row * KW)[c4];
        *reinterpret_cast<uint4*>(&sW[0][row][c4 * 4]) = v;
    }
    __syncthreads();

    for (int c = 0; c < NCH; ++c) {
        const int cur = c & 1;
        const bool pf = (c + 1 < NCH);

        // ---- phase A: issue prefetch loads for chunk c+1 (stay in flight) ----
        float4 xr[16];
        uint4  wr[4];
        if (pf) {
            #pragma unroll
            for (int rr = 0; rr < 8; ++rr) {
                const float4* src = reinterpret_cast<const float4*>(
                    x + (size_t)(row0 + w * 8 + rr) * INF + (size_t)(c + 1) * 512);
                xr[rr * 2]     = src[l];
                xr[rr * 2 + 1] = src[64 + l];
            }
            #pragma unroll
            for (int i = 0; i < 4; ++i) {
                int idx = t + 512 * i;
                int row = idx >> 2, c4 = idx & 3;
                wr[i] = reinterpret_cast<const uint4*>(
                    Wp + (size_t)row * KW + (c + 1) * KC)[c4];
            }
        }

        // ---- phase B: compute chunk c from LDS[cur] ----
        #pragma unroll
        for (int k4 = 0; k4 < KC / 4; ++k4) {
            uint4 xv[4];
            #pragma unroll
            for (int i = 0; i < 4; ++i)
                xv[i] = *reinterpret_cast<const uint4*>(&sX[cur][ty + 16 * i][k4 * 4]);
            #pragma unroll
            for (int j = 0; j < 16; ++j) {
                uint4 wv = *reinterpret_cast<const uint4*>(&sW[cur][tx + 32 * j][k4 * 4]);
                #pragma unroll
                for (int i = 0; i < 4; ++i) {
                    acc[i][j] += __popc(xv[i].x ^ wv.x);
                    acc[i][j] += __popc(xv[i].y ^ wv.y);
                    acc[i][j] += __popc(xv[i].z ^ wv.z);
                    acc[i][j] += __popc(xv[i].w ^ wv.w);
                }
            }
        }

        // ---- phase C: consume prefetch into buffer cur^1 ----
        if (pf) {
            #pragma unroll
            for (int rr = 0; rr < 8; ++rr) {
                #pragma unroll
                for (int h = 0; h < 2; ++h) {
                    float4 v = xr[rr * 2 + h];
                    unsigned long long b0 = __ballot(v.x < 0.f);
                    unsigned long long b1 = __ballot(v.y < 0.f);
                    unsigned long long b2 = __ballot(v.z < 0.f);
                    unsigned long long b3 = __ballot(v.w < 0.f);
                    if (l == 0) {
                        uint64_t* d = reinterpret_cast<uint64_t*>(
                            &sX[cur ^ 1][w * 8 + rr][h * 8]);
                        d[0] = b0; d[1] = b1; d[2] = b2; d[3] = b3;
                    }
                }
            }
            #pragma unroll
            for (int i = 0; i < 4; ++i) {
                int idx = t + 512 * i;
                int row = idx >> 2, c4 = idx & 3;
                *reinterpret_cast<uint4*>(&sW[cur ^ 1][row][c4 * 4]) = wr[i];
            }
        }
        __syncthreads();
    }

    // ---- epilogue: C = INF - 2*acc + bias ----
    #pragma unroll
    for (int j = 0; j < 16; ++j) {
        int u = tx + 32 * j;
        float bj = bias[u];
        #pragma unroll
        for (int i = 0; i < 4; ++i) {
            int r = row0 + ty + 16 * i;
            C[(size_t)r * UNITS + u] = (float)(INF - 2 * acc[i][j]) + bj;
        }
    }
}

extern "C" void kernel_launch(void* const* d_in, const int* in_sizes, int n_in,
                              void* d_out, int out_size, void* d_ws, size_t ws_size,
                              hipStream_t stream) {
    const float* x = (const float*)d_in[0];
    const float* W = (const float*)d_in[1];
    const float* b = (const float*)d_in[2];
    float* out = (float*)d_out;

    unsigned long long* Wp = (unsigned long long*)d_ws;   // 256 KB

    pack_w_kernel<<<32768 / 256, 256, 0, stream>>>(W, Wp);
    fused_kernel<<<BATCH / ROWS, 512, 0, stream>>>(
        x, (const uint32_t*)Wp, b, out);
}

// Round 6
// 125.739 us; speedup vs baseline: 4.4399x; 4.4399x over previous
//
#include <hip/hip_runtime.h>
#include <stdint.h>

// Binarized dense: C[r][u] = sum_k sign(x[r][k]) * sign(W[k][u]) + b[u]
//   sign(v) = +1 if v >= 0 else -1   -> bit(v) = (v < 0)
//   dot = F - 2 * popcount(xbits ^ wbits)
//
// Packed layout per row/col (F=4096 bits = 64 u64 words):
//   u64 word w = c*4 + j,  c = 0..15 (256-float chunk), j = 0..3 (float4 comp)
//   bit i (0..63) of word (c,j) = bit(v[c*256 + i*4 + j])
// pack_x (ballot) and pack_w (bit loop) produce identical layouts (verified
// rounds 1/3/4; popcount is order-invariant so any consistent layout works).

#define BATCH  16384
#define INF    4096
#define UNITS  512
#define KW     128      // u32 words per row (4096/32)
#define KW64   64       // u64 words per row

// ---------------- pack x: [16384,4096] f32 -> [16384,64] u64 ----------------
// One wave handles 4 consecutive 256-float chunks of one row (1 KB x 4).
__global__ __launch_bounds__(256) void pack_x_kernel(const float* __restrict__ x,
                                                     unsigned long long* __restrict__ Xp) {
    int wave = blockIdx.x * 4 + (threadIdx.x >> 6);   // 0..65535
    int lane = threadIdx.x & 63;
    int r  = wave >> 2;        // row 0..16383
    int c0 = (wave & 3) * 4;   // first chunk of this wave's group
    const float4* src = reinterpret_cast<const float4*>(x + (size_t)r * INF) + lane;
    #pragma unroll
    for (int cc = 0; cc < 4; ++cc) {
        int c = c0 + cc;
        float4 v = src[c * 64];
        unsigned long long b0 = __ballot(v.x < 0.f);
        unsigned long long b1 = __ballot(v.y < 0.f);
        unsigned long long b2 = __ballot(v.z < 0.f);
        unsigned long long b3 = __ballot(v.w < 0.f);
        if (lane == 0) {
            unsigned long long* dst = Xp + (size_t)r * KW64 + c * 4;
            dst[0] = b0; dst[1] = b1; dst[2] = b2; dst[3] = b3;
        }
    }
}

// ---------------- pack W: [4096,512] f32 -> [512,64] u64 --------------------
__global__ __launch_bounds__(256) void pack_w_kernel(const float* __restrict__ W,
                                                     unsigned long long* __restrict__ Wp) {
    int t  = blockIdx.x * 256 + threadIdx.x;   // 0..32767
    int u  = t & 511;                          // column
    int cj = t >> 9;                           // 0..63 = c*4 + j
    int j  = cj & 3;
    int c  = cj >> 2;
    const float* base = W + (size_t)(c * 256 + j) * UNITS + u;
    unsigned long long m = 0;
    #pragma unroll 16
    for (int i = 0; i < 64; ++i) {
        float v = base[(size_t)(4 * i) * UNITS];
        m |= (unsigned long long)(v < 0.f) << i;
    }
    Wp[(size_t)u * KW64 + cj] = m;
}

// -------- bit-GEMM: 128x128 tile, 8x8 per thread, BK=32 u32 words -----------
// __launch_bounds__(256,1): VGPR cap 256 under either 2nd-arg interpretation;
// demand ~160 (acc 64 + xv/wv 64 + addr) -> no spill, ~3 waves/SIMD by VGPR,
// 3-4 blocks/CU by LDS (36.9 KB).
// Reads: xv rows ty+16i (4 distinct/wave, broadcast, conflict-free);
// wv rows tx+16j (16 distinct, pad-36 -> 2-way, free per m136).
__global__ __launch_bounds__(256, 1) void bgemm_kernel(const uint32_t* __restrict__ Xp,
                                                       const uint32_t* __restrict__ Wp,
                                                       const float* __restrict__ bias,
                                                       float* __restrict__ C) {
    __shared__ uint32_t sX[128][36];
    __shared__ uint32_t sW[128][36];
    const int t  = threadIdx.x;
    const int bx = blockIdx.x;   // col tile 0..3
    const int by = blockIdx.y;   // row tile 0..127
    const int tx = t & 15;
    const int ty = t >> 4;

    int acc[8][8] = {};

    for (int s = 0; s < 4; ++s) {
        if (s) __syncthreads();
        // stage 128 rows x 32 u32 words (= 8 uint4) of each operand
        #pragma unroll
        for (int i = 0; i < 4; ++i) {
            int idx = t + 256 * i;         // 0..1023
            int row = idx >> 3;
            int c4  = idx & 7;
            uint4 vx = reinterpret_cast<const uint4*>(
                Xp + ((size_t)(by * 128 + row)) * KW + s * 32)[c4];
            uint4 vw = reinterpret_cast<const uint4*>(
                Wp + ((size_t)(bx * 128 + row)) * KW + s * 32)[c4];
            *reinterpret_cast<uint4*>(&sX[row][c4 * 4]) = vx;
            *reinterpret_cast<uint4*>(&sW[row][c4 * 4]) = vw;
        }
        __syncthreads();

        #pragma unroll
        for (int k4 = 0; k4 < 8; ++k4) {
            uint4 xv[8], wv[8];
            #pragma unroll
            for (int i = 0; i < 8; ++i)
                xv[i] = *reinterpret_cast<const uint4*>(&sX[ty + 16 * i][k4 * 4]);
            #pragma unroll
            for (int j = 0; j < 8; ++j)
                wv[j] = *reinterpret_cast<const uint4*>(&sW[tx + 16 * j][k4 * 4]);
            #pragma unroll
            for (int i = 0; i < 8; ++i)
                #pragma unroll
                for (int j = 0; j < 8; ++j) {
                    acc[i][j] += __popc(xv[i].x ^ wv[j].x);
                    acc[i][j] += __popc(xv[i].y ^ wv[j].y);
                    acc[i][j] += __popc(xv[i].z ^ wv[j].z);
                    acc[i][j] += __popc(xv[i].w ^ wv[j].w);
                }
        }
    }

    #pragma unroll
    for (int i = 0; i < 8; ++i) {
        int r = by * 128 + ty + 16 * i;
        #pragma unroll
        for (int j = 0; j < 8; ++j) {
            int u = bx * 128 + tx + 16 * j;
            C[(size_t)r * UNITS + u] = (float)(INF - 2 * acc[i][j]) + bias[u];
        }
    }
}

extern "C" void kernel_launch(void* const* d_in, const int* in_sizes, int n_in,
                              void* d_out, int out_size, void* d_ws, size_t ws_size,
                              hipStream_t stream) {
    const float* x = (const float*)d_in[0];
    const float* W = (const float*)d_in[1];
    const float* b = (const float*)d_in[2];
    float* out = (float*)d_out;

    unsigned long long* Wp = (unsigned long long*)d_ws;                       // 256 KB
    unsigned long long* Xp = (unsigned long long*)((char*)d_ws + (1 << 20));  // 8 MB

    pack_w_kernel<<<32768 / 256, 256, 0, stream>>>(W, Wp);
    pack_x_kernel<<<16384, 256, 0, stream>>>(x, Xp);
    bgemm_kernel<<<dim3(UNITS / 128, BATCH / 128), 256, 0, stream>>>(
        (const uint32_t*)Xp, (const uint32_t*)Wp, b, out);
}